// Round 14
// baseline (703.523 us; speedup 1.0000x reference)
//
#include <hip/hip_runtime.h>
#include <math.h>

typedef __attribute__((ext_vector_type(8))) short bf16x8;
typedef __attribute__((ext_vector_type(4))) float f32x4;

__device__ __forceinline__ float b2f(unsigned short u) {
    return __uint_as_float(((unsigned)u) << 16);
}
__device__ __forceinline__ unsigned short f2b(float f) {
    unsigned u = __float_as_uint(f);
    u += 0x7FFF + ((u >> 16) & 1);
    return (unsigned short)(u >> 16);
}
__device__ __forceinline__ void up2(unsigned u, float& a, float& b) {
    a = __uint_as_float(u << 16);
    b = __uint_as_float(u & 0xffff0000u);
}
__device__ __forceinline__ float gelu_exact(float v) {
    return 0.5f * v * (1.0f + erff(v * 0.70710678118654752f));
}
__device__ __forceinline__ void atomicMaxFloat(float* addr, float val) {
    unsigned* ua = (unsigned*)addr;
    unsigned old = *ua;
    while (true) {
        float of = __uint_as_float(old);
        if (of >= val) break;
        unsigned assumed = old;
        old = atomicCAS(ua, assumed, __float_as_uint(val));
        if (old == assumed) break;
    }
}
// async global->LDS, 16B per lane; lds must be the wave-uniform base (dest = base + lane*16)
__device__ __forceinline__ void gl_lds16(const unsigned short* g, unsigned short* lds) {
    __builtin_amdgcn_global_load_lds((const __attribute__((address_space(1))) unsigned int*)g,
                                     (__attribute__((address_space(3))) unsigned int*)lds, 16, 0, 0);
}
// counted vmem wait (immediate must be literal)
template <int N> __device__ __forceinline__ void wait_vm() {
    if constexpr (N == 0) asm volatile("s_waitcnt vmcnt(0)" ::: "memory");
    if constexpr (N == 4) asm volatile("s_waitcnt vmcnt(4)" ::: "memory");
    if constexpr (N == 6) asm volatile("s_waitcnt vmcnt(6)" ::: "memory");
    if constexpr (N == 8) asm volatile("s_waitcnt vmcnt(8)" ::: "memory");
}

// ---------------------------------------------------------------- weight conversion fp32 -> bf16
// block 0 also initializes ksum/kmax (completes before any consumer dispatch).
__global__ __launch_bounds__(256)
void cvt_qkvp(const float* __restrict__ wq, const float* __restrict__ wk, const float* __restrict__ wv,
              const float* __restrict__ prj, unsigned short* __restrict__ wdst,
              unsigned short* __restrict__ pdst, float* __restrict__ ksum, float* __restrict__ kmax) {
    if (blockIdx.x < 48) {
        ksum[blockIdx.x * 256 + threadIdx.x] = 0.0f;
        if (blockIdx.x == 0 && threadIdx.x == 0) *kmax = -3.0e38f;
    }
    int i4 = (blockIdx.x * 256 + threadIdx.x) * 4;
    const float* s; unsigned short* d; int off;
    if (i4 < 1769472) { s = (i4 < 589824) ? wq : (i4 < 1179648 ? wk : wv);
        off = (i4 < 589824) ? i4 : (i4 < 1179648 ? i4 - 589824 : i4 - 1179648);
        d = wdst + i4; }
    else { s = prj; off = i4 - 1769472; d = pdst + off; }
    float4 v = *(const float4*)&s[off];
    ushort4 o; o.x = f2b(v.x); o.y = f2b(v.y); o.z = f2b(v.z); o.w = f2b(v.w);
    *(ushort4*)d = o;
}
__global__ __launch_bounds__(256)
void cvt_ow12(const float* __restrict__ wo, const float* __restrict__ w1, const float* __restrict__ w2,
              unsigned short* __restrict__ dst) {
    int i4 = (blockIdx.x * 256 + threadIdx.x) * 4;
    const float* s; int off;
    if (i4 < 589824) { s = wo; off = i4; }
    else if (i4 < 2949120) { s = w1; off = i4 - 589824; }
    else { s = w2; off = i4 - 2949120; }
    float4 v = *(const float4*)&s[off];
    ushort4 o; o.x = f2b(v.x); o.y = f2b(v.y); o.z = f2b(v.z); o.w = f2b(v.w);
    *(ushort4*)&dst[i4] = o;
}

// ---------------------------------------------------------------- LayerNorm (row = 768), out bf16
template <bool IN_F32>
__global__ __launch_bounds__(256)
void ln_kernel(const void* __restrict__ Xv, const float* __restrict__ G,
               const float* __restrict__ Bb, unsigned short* __restrict__ OUT) {
    int row = blockIdx.x, t = threadIdx.x, wave = t >> 6, lane = t & 63;
    __shared__ float red[4];
    float x0, x1, x2;
    if constexpr (IN_F32) {
        const float* xr = (const float*)Xv + (size_t)row * 768;
        x0 = xr[t]; x1 = xr[t + 256]; x2 = xr[t + 512];
    } else {
        const unsigned short* xr = (const unsigned short*)Xv + (size_t)row * 768;
        x0 = b2f(xr[t]); x1 = b2f(xr[t + 256]); x2 = b2f(xr[t + 512]);
    }
    float s = x0 + x1 + x2;
#pragma unroll
    for (int d = 32; d; d >>= 1) s += __shfl_xor(s, d, 64);
    if (lane == 0) red[wave] = s;
    __syncthreads();
    float mean = (red[0] + red[1] + red[2] + red[3]) * (1.0f / 768.0f);
    __syncthreads();
    float d0 = x0 - mean, d1 = x1 - mean, d2 = x2 - mean;
    float s2 = d0 * d0 + d1 * d1 + d2 * d2;
#pragma unroll
    for (int d = 32; d; d >>= 1) s2 += __shfl_xor(s2, d, 64);
    if (lane == 0) red[wave] = s2;
    __syncthreads();
    float var = (red[0] + red[1] + red[2] + red[3]) * (1.0f / 768.0f);
    float inv = rsqrtf(var + 1e-5f);
    size_t base = (size_t)row * 768;
    OUT[base + t]       = f2b(d0 * inv * G[t]       + Bb[t]);
    OUT[base + t + 256] = f2b(d1 * inv * G[t + 256] + Bb[t + 256]);
    OUT[base + t + 512] = f2b(d2 * inv * G[t + 512] + Bb[t + 512]);
}

// ---------------------------------------------------------------- 256x256 gemm_bt, BK=64 dbuf, 8 waves
// BEST-MEASURED 2-PHASE STRUCTURE (kept for wo / FFN-down / QKV).
template <int EPI, bool R_F32, bool C_F32>
__global__ __launch_bounds__(512, 2)
void gemm_bt_256(const unsigned short* __restrict__ A, const unsigned short* __restrict__ Bm,
                 const float* __restrict__ bias, const void* __restrict__ R,
                 void* __restrict__ C, int N, int K, float alpha) {
    __shared__ unsigned short sA[2][256 * 64];
    __shared__ unsigned short sB[2][256 * 64];
    const int t = threadIdx.x;
    const int wave = t >> 6, lane = t & 63, quad = lane >> 4, l16 = lane & 15;
    const int nwg = gridDim.x * gridDim.y;
    int flat = blockIdx.y * gridDim.x + blockIdx.x;
    int q = nwg >> 3, r = nwg & 7;
    int xcd = flat & 7, idx = flat >> 3;
    int swz = (xcd < r ? xcd * (q + 1) : r * (q + 1) + (xcd - r) * q) + idx;
    const int m0 = (swz / gridDim.x) * 256;
    const int n0 = (swz % gridDim.x) * 256;
    const int wm = (wave >> 2) * 128, wn = (wave & 3) * 64;
    const int srow = t >> 3;
    const int scol = ((t & 7) ^ (srow & 7)) << 3;
    const unsigned short* gA = &A[(size_t)(m0 + srow) * K + scol];
    const unsigned short* gB = &Bm[(size_t)(n0 + srow) * K + scol];
    const size_t rstep = (size_t)64 * K;
    unsigned short* ldA0 = &sA[0][wave * 512];
    unsigned short* ldB0 = &sB[0][wave * 512];
    unsigned short* ldA1 = &sA[1][wave * 512];
    unsigned short* ldB1 = &sB[1][wave * 512];
    const int k0off = ((quad ^ (l16 & 7)) & 7) << 3;
    const int k1off = (((4 | quad) ^ (l16 & 7)) & 7) << 3;
    f32x4 acc[8][4] = {};
    const int nt = K >> 6;
#pragma unroll
    for (int u = 0; u < 4; ++u) {
        gl_lds16(gA + u * rstep, ldA0 + u * 4096);
        gl_lds16(gB + u * rstep, ldB0 + u * 4096);
    }
    __syncthreads();
    int cur = 0;
    for (int it = 0; it < nt; ++it) {
        if (it + 1 < nt) {
            const size_t kt = (size_t)(it + 1) << 6;
            unsigned short* dA = cur ? ldA0 : ldA1;
            unsigned short* dB = cur ? ldB0 : ldB1;
#pragma unroll
            for (int u = 0; u < 4; ++u) {
                gl_lds16(gA + u * rstep + kt, dA + u * 4096);
                gl_lds16(gB + u * rstep + kt, dB + u * 4096);
            }
        }
        const unsigned short* bufA = cur ? &sA[1][0] : &sA[0][0];
        const unsigned short* bufB = cur ? &sB[1][0] : &sB[0][0];
#pragma unroll
        for (int ks = 0; ks < 2; ++ks) {
            const int koff = ks ? k1off : k0off;
            bf16x8 bfr[4];
#pragma unroll
            for (int j = 0; j < 4; ++j)
                bfr[j] = *(const bf16x8*)&bufB[(wn + j * 16 + l16) * 64 + koff];
#pragma unroll
            for (int i = 0; i < 8; ++i) {
                bf16x8 af = *(const bf16x8*)&bufA[(wm + i * 16 + l16) * 64 + koff];
#pragma unroll
                for (int j = 0; j < 4; ++j)
                    acc[i][j] = __builtin_amdgcn_mfma_f32_16x16x32_bf16(af, bfr[j], acc[i][j], 0, 0, 0);
            }
        }
        __syncthreads();
        cur ^= 1;
    }
    if constexpr (EPI == 3) {
#pragma unroll
        for (int i = 0; i < 8; ++i) {
            int rowb = m0 + wm + i * 16 + quad * 4;
            int b_ = rowb >> 12, sbase = rowb & 4095;
#pragma unroll
            for (int j = 0; j < 4; ++j) {
                int col = n0 + wn + j * 16 + l16;
                float bs = bias[col];
                ushort4 o;
                o.x = f2b(acc[i][j][0] + bs);
                o.y = f2b(acc[i][j][1] + bs);
                o.z = f2b(acc[i][j][2] + bs);
                o.w = f2b(acc[i][j][3] + bs);
                size_t dst = (((size_t)b_ * 12 + (col >> 6)) * 64 + (col & 63)) * 4096 + sbase;
                *(ushort4*)&((unsigned short*)C)[dst] = o;
            }
        }
        return;
    }
#pragma unroll
    for (int i = 0; i < 8; ++i) {
        int rowb = m0 + wm + i * 16 + quad * 4;
#pragma unroll
        for (int j = 0; j < 4; ++j) {
            int col = n0 + wn + j * 16 + l16;
            float bs = bias[col];
#pragma unroll
            for (int r4 = 0; r4 < 4; ++r4) {
                size_t idx = (size_t)(rowb + r4) * N + col;
                float v = acc[i][j][r4] + bs;
                if constexpr (EPI == 0) v *= alpha;
                if constexpr (EPI == 1) {
                    if constexpr (R_F32) v += ((const float*)R)[idx];
                    else                 v += b2f(((const unsigned short*)R)[idx]);
                }
                if constexpr (EPI == 2) v = gelu_exact(v);
                if constexpr (C_F32) ((float*)C)[idx] = v;
                else                 ((unsigned short*)C)[idx] = f2b(v);
            }
        }
    }
}

// ---------------------------------------------------------------- 256x256 gemm, 8-phase counted-vmcnt
// Faithful T3+T4+T5 port (m201 schedule), FFN-up only this round. Per K-tile: 4 phases =
// C-quadrants (qi,qj). LDS halves: A split by qi (logical rows {0-63,128-191} stored at phys
// [0,128)), B split by qj (rows {0-31,64-95,128-159,192-223} at phys [0,128)) so each half
// DIES mid-group: AH0 after p1, BH0 after p2, AH1/BH1 after p3. Next same-buffer tile's halves
// stage 1/phase with 2-phase lag: p0:AH1(kt+1) p1:BH1(kt+1) p2:AH0(kt+2) p3:BH0(kt+2).
// Counted waits pre-closing-barrier (the barrier broadcasts certification to all waves'
// pre-barrier ds_reads of the NEXT phase): p0 -> vmcnt(6), p3 -> vmcnt(8) (tail 4/0).
// Queue never drains except genuine tail. Phys-row&7 == l16&7 everywhere -> koff unchanged,
// 0 bank conflicts. Per-fragment accumulation order identical to 2-phase (bit-identical C).
template <int EPI, bool R_F32, bool C_F32>
__global__ __launch_bounds__(512, 2)
void gemm_8ph(const unsigned short* __restrict__ A, const unsigned short* __restrict__ Bm,
              const float* __restrict__ bias, const void* __restrict__ R,
              void* __restrict__ C, int N, int K, float alpha) {
    __shared__ unsigned short sA[2][256 * 64];
    __shared__ unsigned short sB[2][256 * 64];
    const int t = threadIdx.x;
    const int wave = t >> 6, lane = t & 63, quad = lane >> 4, l16 = lane & 15;
    const int nwg = gridDim.x * gridDim.y;
    int flat = blockIdx.y * gridDim.x + blockIdx.x;
    int q = nwg >> 3, r = nwg & 7;
    int xcd = flat & 7, idx = flat >> 3;
    int swz = (xcd < r ? xcd * (q + 1) : r * (q + 1) + (xcd - r) * q) + idx;
    const int m0 = (swz / gridDim.x) * 256;
    const int n0 = (swz % gridDim.x) * 256;
    const int wm = (wave >> 2) * 128, wn = (wave & 3) * 64;
    const int aw = (wave >> 2) * 64;   // A phys sub-offset within qi-half
    const int bw = (wave & 3) * 32;    // B phys sub-offset within qj-half
    const int srow = t >> 3;
    const int scol = ((t & 7) ^ (srow & 7)) << 3;
    const int k0off = ((quad ^ (l16 & 7)) & 7) << 3;
    const int k1off = (((4 | quad) ^ (l16 & 7)) & 7) << 3;
    const int brow = ((t >> 3) & 31);  // B source row low bits
    const int bg   = (t >> 8);         // 0/1: which 64-row logical group within a call
    f32x4 acc[8][4] = {};
    const int NT = K >> 6;
    // A half h (qi): phys rows [h*128,h*128+128) <- logical rows {h*64+s, 128+h*64+s}
    auto STAGE_A = [&](int tile, int h) {
        unsigned short* d = &sA[tile & 1][h * 8192 + wave * 512];
        const size_t kb = (size_t)tile << 6;
        gl_lds16(&A[(size_t)(m0 + h * 64 + srow) * K + kb + scol], d);
        gl_lds16(&A[(size_t)(m0 + 128 + h * 64 + srow) * K + kb + scol], d + 4096);
    };
    // B half j (qj): phys rows [j*128,+128) <- logical rows (2g+bg)*64 + j*32 + brow
    auto STAGE_B = [&](int tile, int j) {
        unsigned short* d = &sB[tile & 1][j * 8192 + wave * 512];
        const size_t kb = (size_t)tile << 6;
        gl_lds16(&Bm[(size_t)(n0 + (0 + bg) * 64 + j * 32 + brow) * K + kb + scol], d);
        gl_lds16(&Bm[(size_t)(n0 + (2 + bg) * 64 + j * 32 + brow) * K + kb + scol], d + 4096);
    };
    // prologue: mimic steady-state stream for tile 0 (+ AH0/BH0 of tile 1)
    STAGE_A(0, 0); STAGE_B(0, 0); STAGE_A(0, 1); STAGE_B(0, 1);
    STAGE_A(1, 0); STAGE_B(1, 0);
    wait_vm<8>();                      // certify AH0(0), BH0(0)
    __builtin_amdgcn_s_barrier();
    for (int kt = 0; kt < NT; ++kt) {
        const unsigned short* bA = sA[kt & 1];
        const unsigned short* bB = sB[kt & 1];
        const bool s1 = (kt + 1 < NT), s2 = (kt + 2 < NT);
#pragma unroll
        for (int p = 0; p < 4; ++p) {
            const int qi = p >> 1, qj = p & 1;
            bf16x8 afr[4][2], bfr[2][2];
#pragma unroll
            for (int ii = 0; ii < 4; ++ii)
#pragma unroll
                for (int ks = 0; ks < 2; ++ks)
                    afr[ii][ks] = *(const bf16x8*)&bA[(qi * 128 + aw + ii * 16 + l16) * 64 + (ks ? k1off : k0off)];
#pragma unroll
            for (int jj = 0; jj < 2; ++jj)
#pragma unroll
                for (int ks = 0; ks < 2; ++ks)
                    bfr[jj][ks] = *(const bf16x8*)&bB[(qj * 128 + bw + jj * 16 + l16) * 64 + (ks ? k1off : k0off)];
            if (p == 0 && s1) STAGE_A(kt + 1, 1);
            if (p == 1 && s1) STAGE_B(kt + 1, 1);
            if (p == 2 && s2) STAGE_A(kt + 2, 0);
            if (p == 3 && s2) STAGE_B(kt + 2, 0);
            __builtin_amdgcn_s_barrier();
            __builtin_amdgcn_s_setprio(1);
#pragma unroll
            for (int ii = 0; ii < 4; ++ii)
#pragma unroll
                for (int jj = 0; jj < 2; ++jj)
#pragma unroll
                    for (int ks = 0; ks < 2; ++ks)
                        acc[qi * 4 + ii][qj * 2 + jj] = __builtin_amdgcn_mfma_f32_16x16x32_bf16(
                            afr[ii][ks], bfr[jj][ks], acc[qi * 4 + ii][qj * 2 + jj], 0, 0, 0);
            __builtin_amdgcn_s_setprio(0);
            if (p == 0) { if (s1) wait_vm<6>(); else wait_vm<0>(); }
            if (p == 3 && s1) { if (s2) wait_vm<8>(); else wait_vm<4>(); }
            __builtin_amdgcn_s_barrier();
        }
    }
    if constexpr (EPI == 3) {
#pragma unroll
        for (int i = 0; i < 8; ++i) {
            int rowb = m0 + wm + i * 16 + quad * 4;
            int b_ = rowb >> 12, sbase = rowb & 4095;
#pragma unroll
            for (int j = 0; j < 4; ++j) {
                int col = n0 + wn + j * 16 + l16;
                float bs = bias[col];
                ushort4 o;
                o.x = f2b(acc[i][j][0] + bs);
                o.y = f2b(acc[i][j][1] + bs);
                o.z = f2b(acc[i][j][2] + bs);
                o.w = f2b(acc[i][j][3] + bs);
                size_t dst = (((size_t)b_ * 12 + (col >> 6)) * 64 + (col & 63)) * 4096 + sbase;
                *(ushort4*)&((unsigned short*)C)[dst] = o;
            }
        }
        return;
    }
#pragma unroll
    for (int i = 0; i < 8; ++i) {
        int rowb = m0 + wm + i * 16 + quad * 4;
#pragma unroll
        for (int j = 0; j < 4; ++j) {
            int col = n0 + wn + j * 16 + l16;
            float bs = bias[col];
#pragma unroll
            for (int r4 = 0; r4 < 4; ++r4) {
                size_t idx = (size_t)(rowb + r4) * N + col;
                float v = acc[i][j][r4] + bs;
                if constexpr (EPI == 0) v *= alpha;
                if constexpr (EPI == 1) {
                    if constexpr (R_F32) v += ((const float*)R)[idx];
                    else                 v += b2f(((const unsigned short*)R)[idx]);
                }
                if constexpr (EPI == 2) v = gelu_exact(v);
                if constexpr (C_F32) ((float*)C)[idx] = v;
                else                 ((unsigned short*)C)[idx] = f2b(v);
            }
        }
    }
}

// ---------------------------------------------------------------- fused QKV projection
__global__ __launch_bounds__(512, 2)
void gemm_qkv(const unsigned short* __restrict__ A, const unsigned short* __restrict__ Bm,
              const float* __restrict__ BQ, const float* __restrict__ BK,
              const float* __restrict__ BV, unsigned short* __restrict__ Cq,
              unsigned short* __restrict__ Ck, unsigned short* __restrict__ VT, float alpha) {
    const int K = 768;
    __shared__ unsigned short sA[2][256 * 64];
    __shared__ unsigned short sB[2][256 * 64];
    const int t = threadIdx.x;
    const int wave = t >> 6, lane = t & 63, quad = lane >> 4, l16 = lane & 15;
    const int nwg = gridDim.x * gridDim.y;
    int flat = blockIdx.y * gridDim.x + blockIdx.x;
    int q = nwg >> 3, r = nwg & 7;
    int xcd = flat & 7, idx = flat >> 3;
    int swz = (xcd < r ? xcd * (q + 1) : r * (q + 1) + (xcd - r) * q) + idx;
    const int m0 = (swz / gridDim.x) * 256;
    const int n0 = (swz % gridDim.x) * 256;
    const int wm = (wave >> 2) * 128, wn = (wave & 3) * 64;
    const int srow = t >> 3;
    const int scol = ((t & 7) ^ (srow & 7)) << 3;
    const unsigned short* gA = &A[(size_t)(m0 + srow) * K + scol];
    const unsigned short* gB = &Bm[(size_t)(n0 + srow) * K + scol];
    const size_t rstep = (size_t)64 * K;
    unsigned short* ldA0 = &sA[0][wave * 512];
    unsigned short* ldB0 = &sB[0][wave * 512];
    unsigned short* ldA1 = &sA[1][wave * 512];
    unsigned short* ldB1 = &sB[1][wave * 512];
    const int k0off = ((quad ^ (l16 & 7)) & 7) << 3;
    const int k1off = (((4 | quad) ^ (l16 & 7)) & 7) << 3;
    f32x4 acc[8][4] = {};
    const int nt = K >> 6;   // 12
#pragma unroll
    for (int u = 0; u < 4; ++u) {
        gl_lds16(gA + u * rstep, ldA0 + u * 4096);
        gl_lds16(gB + u * rstep, ldB0 + u * 4096);
    }
    __syncthreads();
    int cur = 0;
    for (int it = 0; it < nt; ++it) {
        if (it + 1 < nt) {
            const size_t kt = (size_t)(it + 1) << 6;
            unsigned short* dA = cur ? ldA0 : ldA1;
            unsigned short* dB = cur ? ldB0 : ldB1;
#pragma unroll
            for (int u = 0; u < 4; ++u) {
                gl_lds16(gA + u * rstep + kt, dA + u * 4096);
                gl_lds16(gB + u * rstep + kt, dB + u * 4096);
            }
        }
        const unsigned short* bufA = cur ? &sA[1][0] : &sA[0][0];
        const unsigned short* bufB = cur ? &sB[1][0] : &sB[0][0];
#pragma unroll
        for (int ks = 0; ks < 2; ++ks) {
            const int koff = ks ? k1off : k0off;
            bf16x8 bfr[4];
#pragma unroll
            for (int j = 0; j < 4; ++j)
                bfr[j] = *(const bf16x8*)&bufB[(wn + j * 16 + l16) * 64 + koff];
#pragma unroll
            for (int i = 0; i < 8; ++i) {
                bf16x8 af = *(const bf16x8*)&bufA[(wm + i * 16 + l16) * 64 + koff];
#pragma unroll
                for (int j = 0; j < 4; ++j)
                    acc[i][j] = __builtin_amdgcn_mfma_f32_16x16x32_bf16(af, bfr[j], acc[i][j], 0, 0, 0);
            }
        }
        __syncthreads();
        cur ^= 1;
    }
    const int seg = n0 / 768;            // 0=q, 1=k, 2=v (block never straddles)
    const int nbase = n0 - seg * 768;
    const float* bias = (seg == 0) ? BQ : (seg == 1 ? BK : BV);
    if (seg == 2) {
#pragma unroll
        for (int i = 0; i < 8; ++i) {
            int rowb = m0 + wm + i * 16 + quad * 4;
            int b_ = rowb >> 12, sbase = rowb & 4095;
#pragma unroll
            for (int j = 0; j < 4; ++j) {
                int col = nbase + wn + j * 16 + l16;
                float bs = bias[col];
                ushort4 o;
                o.x = f2b(acc[i][j][0] + bs);
                o.y = f2b(acc[i][j][1] + bs);
                o.z = f2b(acc[i][j][2] + bs);
                o.w = f2b(acc[i][j][3] + bs);
                size_t dst = (((size_t)b_ * 12 + (col >> 6)) * 64 + (col & 63)) * 4096 + sbase;
                *(ushort4*)&VT[dst] = o;
            }
        }
    } else {
        unsigned short* Cn = (seg == 0) ? Cq : Ck;
#pragma unroll
        for (int i = 0; i < 8; ++i) {
            int rowb = m0 + wm + i * 16 + quad * 4;
#pragma unroll
            for (int j = 0; j < 4; ++j) {
                int col = nbase + wn + j * 16 + l16;
                float bs = bias[col];
#pragma unroll
                for (int r4 = 0; r4 < 4; ++r4) {
                    size_t idxo = (size_t)(rowb + r4) * 768 + col;
                    Cn[idxo] = f2b((acc[i][j][r4] + bs) * alpha);
                }
            }
        }
    }
}

// ---------------------------------------------------------------- FAVOR+ key features
template <int MODE>
__global__ __launch_bounds__(256)
void feat_kernel(const unsigned short* __restrict__ Q, const unsigned short* __restrict__ P,
                 unsigned short* __restrict__ OUTP, float* __restrict__ kmaxp,
                 float* __restrict__ ksump) {
    __shared__ unsigned short sQ[64 * 64];
    __shared__ unsigned short sP[256 * 64];
    __shared__ float sDiag[64];
    __shared__ float sRed[4];
    int t = threadIdx.x, wave = t >> 6, lane = t & 63, quad = lane >> 4, l16 = lane & 15;
    int bh = blockIdx.y, bq = bh / 12, hh = bh % 12;
    int s0 = blockIdx.x * 64;
    size_t rowbase = (size_t)bq * 4096 + s0;
#pragma unroll
    for (int u = 0; u < 2; ++u) {
        int L = u * 256 + t, row = L >> 3, c8 = (L & 7) * 8;
        *(uint4*)&sQ[row * 64 + c8] = *(const uint4*)&Q[(rowbase + row) * 768 + hh * 64 + c8];
    }
#pragma unroll
    for (int u = 0; u < 8; ++u) {
        int L = u * 256 + t, row = L >> 3, c8 = (L & 7) * 8;
        *(uint4*)&sP[row * 64 + c8] = *(const uint4*)&P[(size_t)row * 64 + c8];
    }
    __syncthreads();
    if (MODE != 1 && t < 64) {
        float d = 0.0f;
        for (int c = 0; c < 64; ++c) { float f = b2f(sQ[t * 64 + c]); d += f * f; }
        sDiag[t] = 0.5f * d;
    }
    f32x4 acc[4][4] = {};
#pragma unroll
    for (int ks = 0; ks < 2; ++ks) {
        bf16x8 af[4], bfr[4];
#pragma unroll
        for (int i = 0; i < 4; ++i) af[i] = *(const bf16x8*)&sQ[(i * 16 + l16) * 64 + ks * 32 + quad * 8];
#pragma unroll
        for (int j = 0; j < 4; ++j) bfr[j] = *(const bf16x8*)&sP[(wave * 64 + j * 16 + l16) * 64 + ks * 32 + quad * 8];
#pragma unroll
        for (int i = 0; i < 4; ++i)
#pragma unroll
            for (int j = 0; j < 4; ++j)
                acc[i][j] = __builtin_amdgcn_mfma_f32_16x16x32_bf16(af[i], bfr[j], acc[i][j], 0, 0, 0);
    }
    if constexpr (MODE == 1) {
        float m = -3.0e38f;
#pragma unroll
        for (int i = 0; i < 4; ++i)
#pragma unroll
            for (int j = 0; j < 4; ++j)
#pragma unroll
                for (int r = 0; r < 4; ++r) m = fmaxf(m, acc[i][j][r]);
#pragma unroll
        for (int d = 1; d < 64; d <<= 1) m = fmaxf(m, __shfl_xor(m, d, 64));
        if (lane == 0) sRed[wave] = m;
        __syncthreads();
        if (t == 0) atomicMaxFloat(kmaxp, fmaxf(fmaxf(sRed[0], sRed[1]), fmaxf(sRed[2], sRed[3])));
        return;
    } else {  // MODE == 2
        __syncthreads();  // sDiag visibility
        float mx_k = *kmaxp;
        float csum[4] = {0.0f, 0.0f, 0.0f, 0.0f};
#pragma unroll
        for (int i = 0; i < 4; ++i)
#pragma unroll
            for (int j = 0; j < 4; ++j) {
                int col = wave * 64 + j * 16 + l16;
                ushort4 o;
#pragma unroll
                for (int r = 0; r < 4; ++r) {
                    int row = i * 16 + quad * 4 + r;
                    float v = 0.0625f * (expf(acc[i][j][r] - sDiag[row] - mx_k) + 1e-4f);
                    csum[j] += v;
                    (&o.x)[r] = f2b(v);
                }
                *(ushort4*)&OUTP[((size_t)bh * 256 + col) * 4096 + s0 + i * 16 + quad * 4] = o;
            }
#pragma unroll
        for (int j = 0; j < 4; ++j) {
            csum[j] += __shfl_xor(csum[j], 16, 64);
            csum[j] += __shfl_xor(csum[j], 32, 64);
        }
        if (quad == 0)
#pragma unroll
            for (int j = 0; j < 4; ++j)
                atomicAdd(&ksump[bh * 256 + wave * 64 + j * 16 + l16], csum[j]);
    }
}

// ---------------------------------------------------------------- ctx = kp^T @ v via MFMA
__global__ __launch_bounds__(256)
void ctx_gemm(const unsigned short* __restrict__ KPT, const unsigned short* __restrict__ VT,
              float* __restrict__ part) {
    __shared__ unsigned short sV[2][64 * 32];
    __shared__ unsigned short sK[2][128 * 32];
    const int t = threadIdx.x;
    const int wave = t >> 6, lane = t & 63, quad = lane >> 4, l16 = lane & 15;
    const int bh = blockIdx.y;
    const int sc = blockIdx.x >> 1, mh = blockIdx.x & 1;
    const int m0 = mh * 128;
    const int k0 = sc * 512;
    const int srow = t >> 2;
    const int scol = ((t & 3) ^ (srow & 3)) << 3;
    const unsigned short* gv  = &VT [((size_t)bh * 64 + srow) * 4096 + k0 + scol];
    const unsigned short* gk0 = &KPT[((size_t)bh * 256 + m0 + srow) * 4096 + k0 + scol];
    const unsigned short* gk1 = &KPT[((size_t)bh * 256 + m0 + 64 + srow) * 4096 + k0 + scol];
    const int ldsoff = wave * 512;
    const int sw = ((quad ^ l16) & 3) << 3;
    f32x4 acc[4][2] = {};
    gl_lds16(gv,  &sV[0][ldsoff]);
    gl_lds16(gk0, &sK[0][ldsoff]);
    gl_lds16(gk1, &sK[0][2048 + ldsoff]);
    __syncthreads();
    int cur = 0;
    for (int it = 0; it < 16; ++it) {
        if (it + 1 < 16) {
            const int kt = (it + 1) << 5;
            gl_lds16(gv + kt,  &sV[cur ^ 1][ldsoff]);
            gl_lds16(gk0 + kt, &sK[cur ^ 1][ldsoff]);
            gl_lds16(gk1 + kt, &sK[cur ^ 1][2048 + ldsoff]);
        }
        bf16x8 af[4], bfr[2];
#pragma unroll
        for (int i = 0; i < 4; ++i) af[i] = *(const bf16x8*)&sV[cur][(i * 16 + l16) * 32 + sw];
#pragma unroll
        for (int j = 0; j < 2; ++j) bfr[j] = *(const bf16x8*)&sK[cur][(wave * 32 + j * 16 + l16) * 32 + sw];
#pragma unroll
        for (int i = 0; i < 4; ++i)
#pragma unroll
            for (int j = 0; j < 2; ++j)
                acc[i][j] = __builtin_amdgcn_mfma_f32_16x16x32_bf16(af[i], bfr[j], acc[i][j], 0, 0, 0);
        __syncthreads();
        cur ^= 1;
    }
    float* base = part + ((size_t)(sc * 48 + bh) * 64) * 256;
#pragma unroll
    for (int i = 0; i < 4; ++i)
#pragma unroll
        for (int r = 0; r < 4; ++r) {
            int d = i * 16 + quad * 4 + r;
#pragma unroll
            for (int j = 0; j < 2; ++j) {
                int m = m0 + wave * 32 + j * 16 + l16;
                base[(size_t)d * 256 + m] = acc[i][j][r];
            }
        }
}

__global__ __launch_bounds__(256)
void ctx_reduce(const float* __restrict__ part, unsigned short* __restrict__ ctxb) {
    size_t i = (size_t)blockIdx.x * 256 + threadIdx.x;  // over 48*64*256
    float s = 0.0f;
#pragma unroll
    for (int c = 0; c < 8; ++c) s += part[(size_t)c * 786432 + i];
    ctxb[i] = f2b(s);
}

// ---------------------------------------------------------------- fused query-features + attn
__global__ __launch_bounds__(256)
void feat_attn(const unsigned short* __restrict__ Q, const unsigned short* __restrict__ P,
               const unsigned short* __restrict__ CTX, const float* __restrict__ ksump,
               unsigned short* __restrict__ ATT) {
    __shared__ unsigned short sQ[64 * 64];
    __shared__ unsigned short sPQ[256 * 64];
    __shared__ unsigned short sCtx[64 * 256];
    __shared__ float sDiag[64];
    __shared__ float sRed[256];
    __shared__ float sWred[256];
    __shared__ float sKs[256];
    __shared__ float sDinv[64];
    int t = threadIdx.x, wave = t >> 6, lane = t & 63, quad = lane >> 4, l16 = lane & 15;
    int bh = blockIdx.y, bq = bh / 12, hh = bh % 12;
    int s0 = blockIdx.x * 64;
    size_t rowbase = (size_t)bq * 4096 + s0;
#pragma unroll
    for (int u = 0; u < 2; ++u) {
        int L = u * 256 + t, row = L >> 3, c8 = (L & 7) * 8;
        *(uint4*)&sQ[row * 64 + c8] = *(const uint4*)&Q[(rowbase + row) * 768 + hh * 64 + c8];
    }
#pragma unroll
    for (int u = 0; u < 8; ++u) {
        int L = u * 256 + t, row = L >> 3, c8 = (L & 7) * 8;
        *(uint4*)&sPQ[row * 64 + c8] = *(const uint4*)&P[(size_t)row * 64 + c8];
    }
#pragma unroll
    for (int u = 0; u < 8; ++u) {
        int L = u * 256 + t, d = L >> 5, m8 = L & 31;
        int m8s = (m8 & 28) | ((m8 ^ d) & 3);
        *(uint4*)&sCtx[d * 256 + m8s * 8] = *(const uint4*)&CTX[(size_t)bh * 16384 + d * 256 + m8 * 8];
    }
    sKs[t] = ksump[bh * 256 + t];
    __syncthreads();
    if (t < 64) {
        float d = 0.0f;
        for (int c = 0; c < 64; ++c) { float f = b2f(sQ[t * 64 + c]); d += f * f; }
        sDiag[t] = 0.5f * d;
    }
    f32x4 acc[4][4] = {};
#pragma unroll
    for (int ks = 0; ks < 2; ++ks) {
        bf16x8 af[4], bfr[4];
#pragma unroll
        for (int i = 0; i < 4; ++i) af[i] = *(const bf16x8*)&sQ[(i * 16 + l16) * 64 + ks * 32 + quad * 8];
#pragma unroll
        for (int j = 0; j < 4; ++j) bfr[j] = *(const bf16x8*)&sPQ[(wave * 64 + j * 16 + l16) * 64 + ks * 32 + quad * 8];
#pragma unroll
        for (int i = 0; i < 4; ++i)
#pragma unroll
            for (int j = 0; j < 4; ++j)
                acc[i][j] = __builtin_amdgcn_mfma_f32_16x16x32_bf16(af[i], bfr[j], acc[i][j], 0, 0, 0);
    }
#pragma unroll
    for (int i = 0; i < 4; ++i)
#pragma unroll
        for (int r = 0; r < 4; ++r) {
            float m = fmaxf(fmaxf(acc[i][0][r], acc[i][1][r]), fmaxf(acc[i][2][r], acc[i][3][r]));
#pragma unroll
            for (int d = 1; d < 16; d <<= 1) m = fmaxf(m, __shfl_xor(m, d, 64));
            if (l16 == 0) sRed[wave * 64 + i * 16 + quad * 4 + r] = m;
        }
    __syncthreads();
    if (t < 64) sRed[t] = fmaxf(fmaxf(sRed[t], sRed[64 + t]), fmaxf(sRed[128 + t], sRed[192 + t]));
    __syncthreads();
#pragma unroll
    for (int i = 0; i < 4; ++i)
#pragma unroll
        for (int r = 0; r < 4; ++r) {
            int row = i * 16 + quad * 4 + r;
            float diag = sDiag[row], mx = sRed[row];
            float p = 0.0f;
#pragma unroll
            for (int j = 0; j < 4; ++j) {
                int col = wave * 64 + j * 16 + l16;
                float v = 0.0625f * (expf(acc[i][j][r] - diag - mx) + 1e-4f);
                int colp = (col & ~31) | ((((col >> 3) ^ row) & 3) << 3) | (col & 7);
                sPQ[row * 256 + colp] = f2b(v);
                p += v * sKs[col];
            }
#pragma unroll
            for (int d = 1; d < 16; d <<= 1) p += __shfl_xor(p, d, 64);
            if (l16 == 0) sWred[wave * 64 + row] = p;
        }
    __syncthreads();
    if (t < 64) sDinv[t] = 1.0f / (sWred[t] + sWred[64 + t] + sWred[128 + t] + sWred[192 + t]);
    __syncthreads();
    const int w16 = wave * 16;
    const int aswz = ((quad ^ (l16 & 3)) << 3);
    f32x4 acc2[4] = {};
    const unsigned short* qrow = &sPQ[(w16 + l16) * 256];
#pragma unroll
    for (int kt = 0; kt < 256; kt += 32) {
        bf16x8 af = *(const bf16x8*)&qrow[kt + aswz];
#pragma unroll
        for (int j = 0; j < 4; ++j) {
            bf16x8 bf = *(const bf16x8*)&sCtx[(j * 16 + l16) * 256 + kt + aswz];
            acc2[j] = __builtin_amdgcn_mfma_f32_16x16x32_bf16(af, bf, acc2[j], 0, 0, 0);
        }
    }
#pragma unroll
    for (int rr = 0; rr < 4; ++rr) {
        int sr = w16 + quad * 4 + rr;
        float dv = sDinv[sr];
        size_t obase = ((size_t)bq * 4096 + s0 + sr) * 768 + hh * 64;
#pragma unroll
        for (int j = 0; j < 4; ++j)
            ATT[obase + j * 16 + l16] = f2b(acc2[j][rr] * dv);
    }
}

// ================================================================ host
extern "C" void kernel_launch(void* const* d_in, const int* in_sizes, int n_in,
                              void* d_out, int out_size, void* d_ws, size_t ws_size,
                              hipStream_t stream) {
    const float* X   = (const float*)d_in[0];
    const float* PRJ = (const float*)d_in[1];
    const float* WQ  = (const float*)d_in[2];
    const float* BQ  = (const float*)d_in[3];
    const float* WK  = (const float*)d_in[4];
    const float* BKb = (const float*)d_in[5];
    const float* WV  = (const float*)d_in[6];
    const float* BV  = (const float*)d_in[7];
    const float* WO  = (const float*)d_in[8];
    const float* BO  = (const float*)d_in[9];
    const float* G1  = (const float*)d_in[10];
    const float* Bn1 = (const float*)d_in[11];
    const float* G2  = (const float*)d_in[12];
    const float* Bn2 = (const float*)d_in[13];
    const float* W1  = (const float*)d_in[14];
    const float* Bf1 = (const float*)d_in[15];
    const float* W2  = (const float*)d_in[16];
    const float* Bf2 = (const float*)d_in[17];
    float* OUT = (float*)d_out;

    char* w = (char*)d_ws;
    const size_t SZ_ACT = (size_t)16384 * 768 * 2;  // 25165824
    unsigned short* hbuf  = (unsigned short*)(w);                     // A0
    float*          part  = (float*)(w);                              // A0
    unsigned short* qn    = (unsigned short*)(w + SZ_ACT);            // A1
    unsigned short* wow12 = (unsigned short*)(w + SZ_ACT);            // A1 after feat_attn
    unsigned short* kn    = (unsigned short*)(w + 2 * SZ_ACT);        // A2
    unsigned short* x2    = (unsigned short*)(w + 2 * SZ_ACT);        // A2
    unsigned short* vtb   = (unsigned short*)(w + 3 * SZ_ACT);        // A3
    unsigned short* attn  = (unsigned short*)(w + 3 * SZ_ACT);        // A3
    unsigned short* wqkv  = (unsigned short*)(w + 4 * SZ_ACT);        // A4
    unsigned short* kpt   = (unsigned short*)(w + 4 * SZ_ACT);        // A4
    unsigned short* gmid  = kpt;                                      // A4 after kpT dead
    char* tail = w + 4 * SZ_ACT + (size_t)100663296;
    unsigned short* prjb = (unsigned short*)(tail);
    unsigned short* ctxb = (unsigned short*)(tail + 32768);
    float* ksum = (float*)(tail + 32768 + 1572864);
    float* kmax = (float*)(tail + 32768 + 1572864 + 49152);

    unsigned short* w1b = wow12 + 589824;
    unsigned short* w2b = wow12 + 2949120;
    unsigned short* wob = wow12;

    const float NORM = 0.35355339059327373f;  // 64^-0.25

    cvt_qkvp<<<1744, 256, 0, stream>>>(WQ, WK, WV, PRJ, wqkv, prjb, ksum, kmax);
    ln_kernel<true><<<16384, 256, 0, stream>>>(X, G1, Bn1, hbuf);
    gemm_qkv<<<dim3(9, 64), 512, 0, stream>>>(hbuf, wqkv, BQ, BKb, BV, qn, kn, vtb, NORM);
    feat_kernel<1><<<dim3(64, 48), 256, 0, stream>>>(kn, prjb, nullptr, kmax, ksum);
    feat_kernel<2><<<dim3(64, 48), 256, 0, stream>>>(kn, prjb, kpt, kmax, ksum);
    ctx_gemm<<<dim3(16, 48), 256, 0, stream>>>(kpt, vtb, part);
    ctx_reduce<<<3072, 256, 0, stream>>>(part, ctxb);
    feat_attn<<<dim3(64, 48), 256, 0, stream>>>(qn, prjb, ctxb, ksum, attn);
    cvt_ow12<<<5184, 256, 0, stream>>>(WO, W1, W2, wow12);
    gemm_bt_256<1, true, false><<<dim3(3, 64), 512, 0, stream>>>(attn, wob, BO, X, x2, 768, 768, 1.0f);
    ln_kernel<false><<<16384, 256, 0, stream>>>(x2, G2, Bn2, hbuf);
    // FFN-up on the 8-phase counted-vmcnt schedule (this round's single variable)
    gemm_8ph<2, false, false><<<dim3(12, 64), 512, 0, stream>>>(hbuf, w1b, Bf1, nullptr, gmid, 3072, 768, 1.0f);
    gemm_bt_256<1, false, true><<<dim3(3, 64), 512, 0, stream>>>(gmid, w2b, Bf2, x2, OUT, 768, 3072, 1.0f);
}

// Round 15
// 680.434 us; speedup vs baseline: 1.0339x; 1.0339x over previous
//
#include <hip/hip_runtime.h>
#include <math.h>

typedef __attribute__((ext_vector_type(8))) short bf16x8;
typedef __attribute__((ext_vector_type(4))) float f32x4;

__device__ __forceinline__ float b2f(unsigned short u) {
    return __uint_as_float(((unsigned)u) << 16);
}
__device__ __forceinline__ unsigned short f2b(float f) {
    unsigned u = __float_as_uint(f);
    u += 0x7FFF + ((u >> 16) & 1);
    return (unsigned short)(u >> 16);
}
__device__ __forceinline__ void up2(unsigned u, float& a, float& b) {
    a = __uint_as_float(u << 16);
    b = __uint_as_float(u & 0xffff0000u);
}
__device__ __forceinline__ float gelu_exact(float v) {
    return 0.5f * v * (1.0f + erff(v * 0.70710678118654752f));
}
__device__ __forceinline__ void atomicMaxFloat(float* addr, float val) {
    unsigned* ua = (unsigned*)addr;
    unsigned old = *ua;
    while (true) {
        float of = __uint_as_float(old);
        if (of >= val) break;
        unsigned assumed = old;
        old = atomicCAS(ua, assumed, __float_as_uint(val));
        if (old == assumed) break;
    }
}
// async global->LDS, 16B per lane; lds must be the wave-uniform base (dest = base + lane*16)
__device__ __forceinline__ void gl_lds16(const unsigned short* g, unsigned short* lds) {
    __builtin_amdgcn_global_load_lds((const __attribute__((address_space(1))) unsigned int*)g,
                                     (__attribute__((address_space(3))) unsigned int*)lds, 16, 0, 0);
}

// ---------------------------------------------------------------- weight conversion fp32 -> bf16
// block 0 also initializes ksum/kmax (completes before any consumer dispatch).
__global__ __launch_bounds__(256)
void cvt_qkvp(const float* __restrict__ wq, const float* __restrict__ wk, const float* __restrict__ wv,
              const float* __restrict__ prj, unsigned short* __restrict__ wdst,
              unsigned short* __restrict__ pdst, float* __restrict__ ksum, float* __restrict__ kmax) {
    if (blockIdx.x < 48) {
        ksum[blockIdx.x * 256 + threadIdx.x] = 0.0f;
        if (blockIdx.x == 0 && threadIdx.x == 0) *kmax = -3.0e38f;
    }
    int i4 = (blockIdx.x * 256 + threadIdx.x) * 4;
    const float* s; unsigned short* d; int off;
    if (i4 < 1769472) { s = (i4 < 589824) ? wq : (i4 < 1179648 ? wk : wv);
        off = (i4 < 589824) ? i4 : (i4 < 1179648 ? i4 - 589824 : i4 - 1179648);
        d = wdst + i4; }
    else { s = prj; off = i4 - 1769472; d = pdst + off; }
    float4 v = *(const float4*)&s[off];
    ushort4 o; o.x = f2b(v.x); o.y = f2b(v.y); o.z = f2b(v.z); o.w = f2b(v.w);
    *(ushort4*)d = o;
}
__global__ __launch_bounds__(256)
void cvt_ow12(const float* __restrict__ wo, const float* __restrict__ w1, const float* __restrict__ w2,
              unsigned short* __restrict__ dst) {
    int i4 = (blockIdx.x * 256 + threadIdx.x) * 4;
    const float* s; int off;
    if (i4 < 589824) { s = wo; off = i4; }
    else if (i4 < 2949120) { s = w1; off = i4 - 589824; }
    else { s = w2; off = i4 - 2949120; }
    float4 v = *(const float4*)&s[off];
    ushort4 o; o.x = f2b(v.x); o.y = f2b(v.y); o.z = f2b(v.z); o.w = f2b(v.w);
    *(ushort4*)&dst[i4] = o;
}

// ---------------------------------------------------------------- LayerNorm (row = 768), out bf16
template <bool IN_F32>
__global__ __launch_bounds__(256)
void ln_kernel(const void* __restrict__ Xv, const float* __restrict__ G,
               const float* __restrict__ Bb, unsigned short* __restrict__ OUT) {
    int row = blockIdx.x, t = threadIdx.x, wave = t >> 6, lane = t & 63;
    __shared__ float red[4];
    float x0, x1, x2;
    if constexpr (IN_F32) {
        const float* xr = (const float*)Xv + (size_t)row * 768;
        x0 = xr[t]; x1 = xr[t + 256]; x2 = xr[t + 512];
    } else {
        const unsigned short* xr = (const unsigned short*)Xv + (size_t)row * 768;
        x0 = b2f(xr[t]); x1 = b2f(xr[t + 256]); x2 = b2f(xr[t + 512]);
    }
    float s = x0 + x1 + x2;
#pragma unroll
    for (int d = 32; d; d >>= 1) s += __shfl_xor(s, d, 64);
    if (lane == 0) red[wave] = s;
    __syncthreads();
    float mean = (red[0] + red[1] + red[2] + red[3]) * (1.0f / 768.0f);
    __syncthreads();
    float d0 = x0 - mean, d1 = x1 - mean, d2 = x2 - mean;
    float s2 = d0 * d0 + d1 * d1 + d2 * d2;
#pragma unroll
    for (int d = 32; d; d >>= 1) s2 += __shfl_xor(s2, d, 64);
    if (lane == 0) red[wave] = s2;
    __syncthreads();
    float var = (red[0] + red[1] + red[2] + red[3]) * (1.0f / 768.0f);
    float inv = rsqrtf(var + 1e-5f);
    size_t base = (size_t)row * 768;
    OUT[base + t]       = f2b(d0 * inv * G[t]       + Bb[t]);
    OUT[base + t + 256] = f2b(d1 * inv * G[t + 256] + Bb[t + 256]);
    OUT[base + t + 512] = f2b(d2 * inv * G[t + 512] + Bb[t + 512]);
}

// ---------------------------------------------------------------- 256x256 gemm_bt, BK=64 dbuf, 8 waves
// BEST-MEASURED STRUCTURE (r7: 684, r10: 686, r13: 690 us total — stable plateau). FROZEN:
// rounds 9/11/12/14 each tested one pipeline restructure (counted-vmcnt ring, 3-slot ring,
// BK-halving, faithful 8-phase) and ALL regressed 14-27%. The 2-phase drain is structural
// (m233); beating it needs asm-verified HK-style scheduling beyond this loop's verification
// budget. 512 MFMA per barrier-pair, staged 128 B/MFMA, 8-chunk both-sides swizzle
// (0 bank conflicts), XCD-chunked bijective block swizzle.
// C[m,n] = epi( sum_k A[m,k]*B[n,k] + bias[n] )
// EPI 0: (acc+bias)*alpha   EPI 1: acc+bias+R[m,n]   EPI 2: gelu(acc+bias)
// EPI 3: acc+bias, written TRANSPOSED as vT[b][h][64 d][4096 s]   (V projection)
template <int EPI, bool R_F32, bool C_F32>
__global__ __launch_bounds__(512, 2)
void gemm_bt_256(const unsigned short* __restrict__ A, const unsigned short* __restrict__ Bm,
                 const float* __restrict__ bias, const void* __restrict__ R,
                 void* __restrict__ C, int N, int K, float alpha) {
    __shared__ unsigned short sA[2][256 * 64];
    __shared__ unsigned short sB[2][256 * 64];
    const int t = threadIdx.x;
    const int wave = t >> 6, lane = t & 63, quad = lane >> 4, l16 = lane & 15;
    const int nwg = gridDim.x * gridDim.y;
    int flat = blockIdx.y * gridDim.x + blockIdx.x;
    int q = nwg >> 3, r = nwg & 7;
    int xcd = flat & 7, idx = flat >> 3;
    int swz = (xcd < r ? xcd * (q + 1) : r * (q + 1) + (xcd - r) * q) + idx;
    const int m0 = (swz / gridDim.x) * 256;
    const int n0 = (swz % gridDim.x) * 256;
    const int wm = (wave >> 2) * 128, wn = (wave & 3) * 64;
    const int srow = t >> 3;
    const int scol = ((t & 7) ^ (srow & 7)) << 3;
    const unsigned short* gA = &A[(size_t)(m0 + srow) * K + scol];
    const unsigned short* gB = &Bm[(size_t)(n0 + srow) * K + scol];
    const size_t rstep = (size_t)64 * K;
    unsigned short* ldA0 = &sA[0][wave * 512];
    unsigned short* ldB0 = &sB[0][wave * 512];
    unsigned short* ldA1 = &sA[1][wave * 512];
    unsigned short* ldB1 = &sB[1][wave * 512];
    const int k0off = ((quad ^ (l16 & 7)) & 7) << 3;
    const int k1off = (((4 | quad) ^ (l16 & 7)) & 7) << 3;
    f32x4 acc[8][4] = {};
    const int nt = K >> 6;
#pragma unroll
    for (int u = 0; u < 4; ++u) {
        gl_lds16(gA + u * rstep, ldA0 + u * 4096);
        gl_lds16(gB + u * rstep, ldB0 + u * 4096);
    }
    __syncthreads();
    int cur = 0;
    for (int it = 0; it < nt; ++it) {
        if (it + 1 < nt) {
            const size_t kt = (size_t)(it + 1) << 6;
            unsigned short* dA = cur ? ldA0 : ldA1;
            unsigned short* dB = cur ? ldB0 : ldB1;
#pragma unroll
            for (int u = 0; u < 4; ++u) {
                gl_lds16(gA + u * rstep + kt, dA + u * 4096);
                gl_lds16(gB + u * rstep + kt, dB + u * 4096);
            }
        }
        const unsigned short* bufA = cur ? &sA[1][0] : &sA[0][0];
        const unsigned short* bufB = cur ? &sB[1][0] : &sB[0][0];
#pragma unroll
        for (int ks = 0; ks < 2; ++ks) {
            const int koff = ks ? k1off : k0off;
            bf16x8 bfr[4];
#pragma unroll
            for (int j = 0; j < 4; ++j)
                bfr[j] = *(const bf16x8*)&bufB[(wn + j * 16 + l16) * 64 + koff];
#pragma unroll
            for (int i = 0; i < 8; ++i) {
                bf16x8 af = *(const bf16x8*)&bufA[(wm + i * 16 + l16) * 64 + koff];
#pragma unroll
                for (int j = 0; j < 4; ++j)
                    acc[i][j] = __builtin_amdgcn_mfma_f32_16x16x32_bf16(af, bfr[j], acc[i][j], 0, 0, 0);
            }
        }
        __syncthreads();
        cur ^= 1;
    }
    if constexpr (EPI == 3) {
#pragma unroll
        for (int i = 0; i < 8; ++i) {
            int rowb = m0 + wm + i * 16 + quad * 4;
            int b_ = rowb >> 12, sbase = rowb & 4095;
#pragma unroll
            for (int j = 0; j < 4; ++j) {
                int col = n0 + wn + j * 16 + l16;
                float bs = bias[col];
                ushort4 o;
                o.x = f2b(acc[i][j][0] + bs);
                o.y = f2b(acc[i][j][1] + bs);
                o.z = f2b(acc[i][j][2] + bs);
                o.w = f2b(acc[i][j][3] + bs);
                size_t dst = (((size_t)b_ * 12 + (col >> 6)) * 64 + (col & 63)) * 4096 + sbase;
                *(ushort4*)&((unsigned short*)C)[dst] = o;
            }
        }
        return;
    }
#pragma unroll
    for (int i = 0; i < 8; ++i) {
        int rowb = m0 + wm + i * 16 + quad * 4;
#pragma unroll
        for (int j = 0; j < 4; ++j) {
            int col = n0 + wn + j * 16 + l16;
            float bs = bias[col];
#pragma unroll
            for (int r4 = 0; r4 < 4; ++r4) {
                size_t idx = (size_t)(rowb + r4) * N + col;
                float v = acc[i][j][r4] + bs;
                if constexpr (EPI == 0) v *= alpha;
                if constexpr (EPI == 1) {
                    if constexpr (R_F32) v += ((const float*)R)[idx];
                    else                 v += b2f(((const unsigned short*)R)[idx]);
                }
                if constexpr (EPI == 2) v = gelu_exact(v);
                if constexpr (C_F32) ((float*)C)[idx] = v;
                else                 ((unsigned short*)C)[idx] = f2b(v);
            }
        }
    }
}

// ---------------------------------------------------------------- fused QKV projection
// Same BK=64 K-loop over the contiguous [2304][768] weight block; per-block epilogue
// routing: seg = n0/768 (BN=256 divides 768, no block straddles): 0 -> qn*NORM, 1 -> kn*NORM,
// 2 -> transposed vT write. grid (9,64) = 576 blocks, 1 dispatch.
__global__ __launch_bounds__(512, 2)
void gemm_qkv(const unsigned short* __restrict__ A, const unsigned short* __restrict__ Bm,
              const float* __restrict__ BQ, const float* __restrict__ BK,
              const float* __restrict__ BV, unsigned short* __restrict__ Cq,
              unsigned short* __restrict__ Ck, unsigned short* __restrict__ VT, float alpha) {
    const int K = 768;
    __shared__ unsigned short sA[2][256 * 64];
    __shared__ unsigned short sB[2][256 * 64];
    const int t = threadIdx.x;
    const int wave = t >> 6, lane = t & 63, quad = lane >> 4, l16 = lane & 15;
    const int nwg = gridDim.x * gridDim.y;
    int flat = blockIdx.y * gridDim.x + blockIdx.x;
    int q = nwg >> 3, r = nwg & 7;
    int xcd = flat & 7, idx = flat >> 3;
    int swz = (xcd < r ? xcd * (q + 1) : r * (q + 1) + (xcd - r) * q) + idx;
    const int m0 = (swz / gridDim.x) * 256;
    const int n0 = (swz % gridDim.x) * 256;
    const int wm = (wave >> 2) * 128, wn = (wave & 3) * 64;
    const int srow = t >> 3;
    const int scol = ((t & 7) ^ (srow & 7)) << 3;
    const unsigned short* gA = &A[(size_t)(m0 + srow) * K + scol];
    const unsigned short* gB = &Bm[(size_t)(n0 + srow) * K + scol];
    const size_t rstep = (size_t)64 * K;
    unsigned short* ldA0 = &sA[0][wave * 512];
    unsigned short* ldB0 = &sB[0][wave * 512];
    unsigned short* ldA1 = &sA[1][wave * 512];
    unsigned short* ldB1 = &sB[1][wave * 512];
    const int k0off = ((quad ^ (l16 & 7)) & 7) << 3;
    const int k1off = (((4 | quad) ^ (l16 & 7)) & 7) << 3;
    f32x4 acc[8][4] = {};
    const int nt = K >> 6;   // 12
#pragma unroll
    for (int u = 0; u < 4; ++u) {
        gl_lds16(gA + u * rstep, ldA0 + u * 4096);
        gl_lds16(gB + u * rstep, ldB0 + u * 4096);
    }
    __syncthreads();
    int cur = 0;
    for (int it = 0; it < nt; ++it) {
        if (it + 1 < nt) {
            const size_t kt = (size_t)(it + 1) << 6;
            unsigned short* dA = cur ? ldA0 : ldA1;
            unsigned short* dB = cur ? ldB0 : ldB1;
#pragma unroll
            for (int u = 0; u < 4; ++u) {
                gl_lds16(gA + u * rstep + kt, dA + u * 4096);
                gl_lds16(gB + u * rstep + kt, dB + u * 4096);
            }
        }
        const unsigned short* bufA = cur ? &sA[1][0] : &sA[0][0];
        const unsigned short* bufB = cur ? &sB[1][0] : &sB[0][0];
#pragma unroll
        for (int ks = 0; ks < 2; ++ks) {
            const int koff = ks ? k1off : k0off;
            bf16x8 bfr[4];
#pragma unroll
            for (int j = 0; j < 4; ++j)
                bfr[j] = *(const bf16x8*)&bufB[(wn + j * 16 + l16) * 64 + koff];
#pragma unroll
            for (int i = 0; i < 8; ++i) {
                bf16x8 af = *(const bf16x8*)&bufA[(wm + i * 16 + l16) * 64 + koff];
#pragma unroll
                for (int j = 0; j < 4; ++j)
                    acc[i][j] = __builtin_amdgcn_mfma_f32_16x16x32_bf16(af, bfr[j], acc[i][j], 0, 0, 0);
            }
        }
        __syncthreads();
        cur ^= 1;
    }
    const int seg = n0 / 768;            // 0=q, 1=k, 2=v (block never straddles)
    const int nbase = n0 - seg * 768;
    const float* bias = (seg == 0) ? BQ : (seg == 1 ? BK : BV);
    if (seg == 2) {
        // transposed V write: vT[((b*12+h)*64+d)*4096 + s]
#pragma unroll
        for (int i = 0; i < 8; ++i) {
            int rowb = m0 + wm + i * 16 + quad * 4;
            int b_ = rowb >> 12, sbase = rowb & 4095;
#pragma unroll
            for (int j = 0; j < 4; ++j) {
                int col = nbase + wn + j * 16 + l16;   // 0..767
                float bs = bias[col];
                ushort4 o;
                o.x = f2b(acc[i][j][0] + bs);
                o.y = f2b(acc[i][j][1] + bs);
                o.z = f2b(acc[i][j][2] + bs);
                o.w = f2b(acc[i][j][3] + bs);
                size_t dst = (((size_t)b_ * 12 + (col >> 6)) * 64 + (col & 63)) * 4096 + sbase;
                *(ushort4*)&VT[dst] = o;
            }
        }
    } else {
        unsigned short* Cn = (seg == 0) ? Cq : Ck;
#pragma unroll
        for (int i = 0; i < 8; ++i) {
            int rowb = m0 + wm + i * 16 + quad * 4;
#pragma unroll
            for (int j = 0; j < 4; ++j) {
                int col = nbase + wn + j * 16 + l16;
                float bs = bias[col];
#pragma unroll
                for (int r4 = 0; r4 < 4; ++r4) {
                    size_t idxo = (size_t)(rowb + r4) * 768 + col;
                    Cn[idxo] = f2b((acc[i][j][r4] + bs) * alpha);
                }
            }
        }
    }
}

// ---------------------------------------------------------------- FAVOR+ key features
// MODE 1: key global max. MODE 2: key features written TRANSPOSED kpT[bh][256 m][4096 s]
// + fused ksum column-partials (atomicAdd).
template <int MODE>
__global__ __launch_bounds__(256)
void feat_kernel(const unsigned short* __restrict__ Q, const unsigned short* __restrict__ P,
                 unsigned short* __restrict__ OUTP, float* __restrict__ kmaxp,
                 float* __restrict__ ksump) {
    __shared__ unsigned short sQ[64 * 64];
    __shared__ unsigned short sP[256 * 64];
    __shared__ float sDiag[64];
    __shared__ float sRed[4];
    int t = threadIdx.x, wave = t >> 6, lane = t & 63, quad = lane >> 4, l16 = lane & 15;
    int bh = blockIdx.y, bq = bh / 12, hh = bh % 12;
    int s0 = blockIdx.x * 64;
    size_t rowbase = (size_t)bq * 4096 + s0;
#pragma unroll
    for (int u = 0; u < 2; ++u) {
        int L = u * 256 + t, row = L >> 3, c8 = (L & 7) * 8;
        *(uint4*)&sQ[row * 64 + c8] = *(const uint4*)&Q[(rowbase + row) * 768 + hh * 64 + c8];
    }
#pragma unroll
    for (int u = 0; u < 8; ++u) {
        int L = u * 256 + t, row = L >> 3, c8 = (L & 7) * 8;
        *(uint4*)&sP[row * 64 + c8] = *(const uint4*)&P[(size_t)row * 64 + c8];
    }
    __syncthreads();
    if (MODE != 1 && t < 64) {
        float d = 0.0f;
        for (int c = 0; c < 64; ++c) { float f = b2f(sQ[t * 64 + c]); d += f * f; }
        sDiag[t] = 0.5f * d;
    }
    f32x4 acc[4][4] = {};
#pragma unroll
    for (int ks = 0; ks < 2; ++ks) {
        bf16x8 af[4], bfr[4];
#pragma unroll
        for (int i = 0; i < 4; ++i) af[i] = *(const bf16x8*)&sQ[(i * 16 + l16) * 64 + ks * 32 + quad * 8];
#pragma unroll
        for (int j = 0; j < 4; ++j) bfr[j] = *(const bf16x8*)&sP[(wave * 64 + j * 16 + l16) * 64 + ks * 32 + quad * 8];
#pragma unroll
        for (int i = 0; i < 4; ++i)
#pragma unroll
            for (int j = 0; j < 4; ++j)
                acc[i][j] = __builtin_amdgcn_mfma_f32_16x16x32_bf16(af[i], bfr[j], acc[i][j], 0, 0, 0);
    }
    if constexpr (MODE == 1) {
        float m = -3.0e38f;
#pragma unroll
        for (int i = 0; i < 4; ++i)
#pragma unroll
            for (int j = 0; j < 4; ++j)
#pragma unroll
                for (int r = 0; r < 4; ++r) m = fmaxf(m, acc[i][j][r]);
#pragma unroll
        for (int d = 1; d < 64; d <<= 1) m = fmaxf(m, __shfl_xor(m, d, 64));
        if (lane == 0) sRed[wave] = m;
        __syncthreads();
        if (t == 0) atomicMaxFloat(kmaxp, fmaxf(fmaxf(sRed[0], sRed[1]), fmaxf(sRed[2], sRed[3])));
        return;
    } else {  // MODE == 2
        __syncthreads();  // sDiag visibility
        float mx_k = *kmaxp;
        float csum[4] = {0.0f, 0.0f, 0.0f, 0.0f};
#pragma unroll
        for (int i = 0; i < 4; ++i)
#pragma unroll
            for (int j = 0; j < 4; ++j) {
                int col = wave * 64 + j * 16 + l16;
                ushort4 o;
#pragma unroll
                for (int r = 0; r < 4; ++r) {
                    int row = i * 16 + quad * 4 + r;
                    float v = 0.0625f * (expf(acc[i][j][r] - sDiag[row] - mx_k) + 1e-4f);
                    csum[j] += v;
                    (&o.x)[r] = f2b(v);
                }
                // kpT[bh][col][s0 + i*16 + quad*4 .. +3]
                *(ushort4*)&OUTP[((size_t)bh * 256 + col) * 4096 + s0 + i * 16 + quad * 4] = o;
            }
#pragma unroll
        for (int j = 0; j < 4; ++j) {
            csum[j] += __shfl_xor(csum[j], 16, 64);
            csum[j] += __shfl_xor(csum[j], 32, 64);
        }
        if (quad == 0)
#pragma unroll
            for (int j = 0; j < 4; ++j)
                atomicAdd(&ksump[bh * 256 + wave * 64 + j * 16 + l16], csum[j]);
    }
}

// ---------------------------------------------------------------- ctx = kp^T @ v via MFMA
// KPT[bh][256 m][4096 s], VT[bh][64 d][4096 s].
// grid (16, 48): blockIdx.x = sc*2 + mh; tile [64 d][128 m], K-range = sc*512..+512, BK=32.
// part[sc][bh][64 d][256 m] f32 partials (25 MB, overlays A0); ctx_reduce sums the 8 chunks.
__global__ __launch_bounds__(256)
void ctx_gemm(const unsigned short* __restrict__ KPT, const unsigned short* __restrict__ VT,
              float* __restrict__ part) {
    __shared__ unsigned short sV[2][64 * 32];
    __shared__ unsigned short sK[2][128 * 32];
    const int t = threadIdx.x;
    const int wave = t >> 6, lane = t & 63, quad = lane >> 4, l16 = lane & 15;
    const int bh = blockIdx.y;
    const int sc = blockIdx.x >> 1, mh = blockIdx.x & 1;
    const int m0 = mh * 128;
    const int k0 = sc * 512;
    const int srow = t >> 2;
    const int scol = ((t & 3) ^ (srow & 3)) << 3;
    const unsigned short* gv  = &VT [((size_t)bh * 64 + srow) * 4096 + k0 + scol];
    const unsigned short* gk0 = &KPT[((size_t)bh * 256 + m0 + srow) * 4096 + k0 + scol];
    const unsigned short* gk1 = &KPT[((size_t)bh * 256 + m0 + 64 + srow) * 4096 + k0 + scol];
    const int ldsoff = wave * 512;
    const int sw = ((quad ^ l16) & 3) << 3;
    f32x4 acc[4][2] = {};
    gl_lds16(gv,  &sV[0][ldsoff]);
    gl_lds16(gk0, &sK[0][ldsoff]);
    gl_lds16(gk1, &sK[0][2048 + ldsoff]);
    __syncthreads();
    int cur = 0;
    for (int it = 0; it < 16; ++it) {
        if (it + 1 < 16) {
            const int kt = (it + 1) << 5;
            gl_lds16(gv + kt,  &sV[cur ^ 1][ldsoff]);
            gl_lds16(gk0 + kt, &sK[cur ^ 1][ldsoff]);
            gl_lds16(gk1 + kt, &sK[cur ^ 1][2048 + ldsoff]);
        }
        bf16x8 af[4], bfr[2];
#pragma unroll
        for (int i = 0; i < 4; ++i) af[i] = *(const bf16x8*)&sV[cur][(i * 16 + l16) * 32 + sw];
#pragma unroll
        for (int j = 0; j < 2; ++j) bfr[j] = *(const bf16x8*)&sK[cur][(wave * 32 + j * 16 + l16) * 32 + sw];
#pragma unroll
        for (int i = 0; i < 4; ++i)
#pragma unroll
            for (int j = 0; j < 2; ++j)
                acc[i][j] = __builtin_amdgcn_mfma_f32_16x16x32_bf16(af[i], bfr[j], acc[i][j], 0, 0, 0);
        __syncthreads();
        cur ^= 1;
    }
    float* base = part + ((size_t)(sc * 48 + bh) * 64) * 256;
#pragma unroll
    for (int i = 0; i < 4; ++i)
#pragma unroll
        for (int r = 0; r < 4; ++r) {
            int d = i * 16 + quad * 4 + r;
#pragma unroll
            for (int j = 0; j < 2; ++j) {
                int m = m0 + wave * 32 + j * 16 + l16;
                base[(size_t)d * 256 + m] = acc[i][j][r];
            }
        }
}

__global__ __launch_bounds__(256)
void ctx_reduce(const float* __restrict__ part, unsigned short* __restrict__ ctxb) {
    size_t i = (size_t)blockIdx.x * 256 + threadIdx.x;  // over 48*64*256
    float s = 0.0f;
#pragma unroll
    for (int c = 0; c < 8; ++c) s += part[(size_t)c * 786432 + i];
    ctxb[i] = f2b(s);
}

// ---------------------------------------------------------------- fused query-features + attn
// Per block: 64 q-rows of one (b,h). Phase A = FAVOR+ query features (row-max, exp, row·ksum
// -> dinv in LDS; qp tile written to LDS instead of global). Phase B = attn[64s][64d] =
// qp[64][256] @ ctx^T (ctx stored [d][m], staged swizzled). Saves the 100MB qp round-trip.
__global__ __launch_bounds__(256)
void feat_attn(const unsigned short* __restrict__ Q, const unsigned short* __restrict__ P,
               const unsigned short* __restrict__ CTX, const float* __restrict__ ksump,
               unsigned short* __restrict__ ATT) {
    __shared__ unsigned short sQ[64 * 64];
    __shared__ unsigned short sPQ[256 * 64];   // proj tile; reused as qp[64][256] after phase A reads
    __shared__ unsigned short sCtx[64 * 256];
    __shared__ float sDiag[64];
    __shared__ float sRed[256];
    __shared__ float sWred[256];
    __shared__ float sKs[256];
    __shared__ float sDinv[64];
    int t = threadIdx.x, wave = t >> 6, lane = t & 63, quad = lane >> 4, l16 = lane & 15;
    int bh = blockIdx.y, bq = bh / 12, hh = bh % 12;
    int s0 = blockIdx.x * 64;
    size_t rowbase = (size_t)bq * 4096 + s0;
#pragma unroll
    for (int u = 0; u < 2; ++u) {
        int L = u * 256 + t, row = L >> 3, c8 = (L & 7) * 8;
        *(uint4*)&sQ[row * 64 + c8] = *(const uint4*)&Q[(rowbase + row) * 768 + hh * 64 + c8];
    }
#pragma unroll
    for (int u = 0; u < 8; ++u) {
        int L = u * 256 + t, row = L >> 3, c8 = (L & 7) * 8;
        *(uint4*)&sPQ[row * 64 + c8] = *(const uint4*)&P[(size_t)row * 64 + c8];
    }
    // ctx tile [64 d][256 m], cols swizzled within 32-groups: chunk m8 -> (m8&28)|((m8^d)&3)
#pragma unroll
    for (int u = 0; u < 8; ++u) {
        int L = u * 256 + t, d = L >> 5, m8 = L & 31;
        int m8s = (m8 & 28) | ((m8 ^ d) & 3);
        *(uint4*)&sCtx[d * 256 + m8s * 8] = *(const uint4*)&CTX[(size_t)bh * 16384 + d * 256 + m8 * 8];
    }
    sKs[t] = ksump[bh * 256 + t];
    __syncthreads();
    if (t < 64) {
        float d = 0.0f;
        for (int c = 0; c < 64; ++c) { float f = b2f(sQ[t * 64 + c]); d += f * f; }
        sDiag[t] = 0.5f * d;
    }
    f32x4 acc[4][4] = {};
#pragma unroll
    for (int ks = 0; ks < 2; ++ks) {
        bf16x8 af[4], bfr[4];
#pragma unroll
        for (int i = 0; i < 4; ++i) af[i] = *(const bf16x8*)&sQ[(i * 16 + l16) * 64 + ks * 32 + quad * 8];
#pragma unroll
        for (int j = 0; j < 4; ++j) bfr[j] = *(const bf16x8*)&sPQ[(wave * 64 + j * 16 + l16) * 64 + ks * 32 + quad * 8];
#pragma unroll
        for (int i = 0; i < 4; ++i)
#pragma unroll
            for (int j = 0; j < 4; ++j)
                acc[i][j] = __builtin_amdgcn_mfma_f32_16x16x32_bf16(af[i], bfr[j], acc[i][j], 0, 0, 0);
    }
    // row-wise max over 256 cols
#pragma unroll
    for (int i = 0; i < 4; ++i)
#pragma unroll
        for (int r = 0; r < 4; ++r) {
            float m = fmaxf(fmaxf(acc[i][0][r], acc[i][1][r]), fmaxf(acc[i][2][r], acc[i][3][r]));
#pragma unroll
            for (int d = 1; d < 16; d <<= 1) m = fmaxf(m, __shfl_xor(m, d, 64));
            if (l16 == 0) sRed[wave * 64 + i * 16 + quad * 4 + r] = m;
        }
    __syncthreads();   // also: all sPQ (proj) reads complete after this point
    if (t < 64) sRed[t] = fmaxf(fmaxf(sRed[t], sRed[64 + t]), fmaxf(sRed[128 + t], sRed[192 + t]));
    __syncthreads();
    // exp -> qp into LDS (swizzled cols, same mapping as sCtx) + row-dot-ksum
#pragma unroll
    for (int i = 0; i < 4; ++i)
#pragma unroll
        for (int r = 0; r < 4; ++r) {
            int row = i * 16 + quad * 4 + r;
            float diag = sDiag[row], mx = sRed[row];
            float p = 0.0f;
#pragma unroll
            for (int j = 0; j < 4; ++j) {
                int col = wave * 64 + j * 16 + l16;
                float v = 0.0625f * (expf(acc[i][j][r] - diag - mx) + 1e-4f);
                int colp = (col & ~31) | ((((col >> 3) ^ row) & 3) << 3) | (col & 7);
                sPQ[row * 256 + colp] = f2b(v);
                p += v * sKs[col];
            }
#pragma unroll
            for (int d = 1; d < 16; d <<= 1) p += __shfl_xor(p, d, 64);
            if (l16 == 0) sWred[wave * 64 + row] = p;
        }
    __syncthreads();
    if (t < 64) sDinv[t] = 1.0f / (sWred[t] + sWred[64 + t] + sWred[128 + t] + sWred[192 + t]);
    __syncthreads();
    // phase B: wave owns 16 s-rows; attn = qp @ ctx^T, K = 256
    const int w16 = wave * 16;
    const int aswz = ((quad ^ (l16 & 3)) << 3);   // row&3 == l16&3 for both operands
    f32x4 acc2[4] = {};
    const unsigned short* qrow = &sPQ[(w16 + l16) * 256];
#pragma unroll
    for (int kt = 0; kt < 256; kt += 32) {
        bf16x8 af = *(const bf16x8*)&qrow[kt + aswz];
#pragma unroll
        for (int j = 0; j < 4; ++j) {
            bf16x8 bf = *(const bf16x8*)&sCtx[(j * 16 + l16) * 256 + kt + aswz];
            acc2[j] = __builtin_amdgcn_mfma_f32_16x16x32_bf16(af, bf, acc2[j], 0, 0, 0);
        }
    }
#pragma unroll
    for (int rr = 0; rr < 4; ++rr) {
        int sr = w16 + quad * 4 + rr;
        float dv = sDinv[sr];
        size_t obase = ((size_t)bq * 4096 + s0 + sr) * 768 + hh * 64;
#pragma unroll
        for (int j = 0; j < 4; ++j)
            ATT[obase + j * 16 + l16] = f2b(acc2[j][rr] * dv);
    }
}

// ================================================================ host
extern "C" void kernel_launch(void* const* d_in, const int* in_sizes, int n_in,
                              void* d_out, int out_size, void* d_ws, size_t ws_size,
                              hipStream_t stream) {
    const float* X   = (const float*)d_in[0];
    const float* PRJ = (const float*)d_in[1];
    const float* WQ  = (const float*)d_in[2];
    const float* BQ  = (const float*)d_in[3];
    const float* WK  = (const float*)d_in[4];
    const float* BKb = (const float*)d_in[5];
    const float* WV  = (const float*)d_in[6];
    const float* BV  = (const float*)d_in[7];
    const float* WO  = (const float*)d_in[8];
    const float* BO  = (const float*)d_in[9];
    const float* G1  = (const float*)d_in[10];
    const float* Bn1 = (const float*)d_in[11];
    const float* G2  = (const float*)d_in[12];
    const float* Bn2 = (const float*)d_in[13];
    const float* W1  = (const float*)d_in[14];
    const float* Bf1 = (const float*)d_in[15];
    const float* W2  = (const float*)d_in[16];
    const float* Bf2 = (const float*)d_in[17];
    float* OUT = (float*)d_out;

    // ---- workspace overlays (stream-order lifetimes):
    // A0: hbuf(LN1) -> part(25MB) -> hbuf(LN2)
    // A1: qn -> [wob|w1b|w2b]      A2: kn -> x2      A3: vT -> attn
    // A4 (96 MB): [wqb|wkb|wvb] -> kpT -> gmid
    char* w = (char*)d_ws;
    const size_t SZ_ACT = (size_t)16384 * 768 * 2;  // 25165824
    unsigned short* hbuf  = (unsigned short*)(w);                     // A0
    float*          part  = (float*)(w);                              // A0
    unsigned short* qn    = (unsigned short*)(w + SZ_ACT);            // A1
    unsigned short* wow12 = (unsigned short*)(w + SZ_ACT);            // A1 after feat_attn
    unsigned short* kn    = (unsigned short*)(w + 2 * SZ_ACT);        // A2
    unsigned short* x2    = (unsigned short*)(w + 2 * SZ_ACT);        // A2
    unsigned short* vtb   = (unsigned short*)(w + 3 * SZ_ACT);        // A3 (vT[48][64][4096])
    unsigned short* attn  = (unsigned short*)(w + 3 * SZ_ACT);        // A3
    unsigned short* wqkv  = (unsigned short*)(w + 4 * SZ_ACT);        // A4 (pre-kpT)
    unsigned short* kpt   = (unsigned short*)(w + 4 * SZ_ACT);        // A4 (kpT[48][256][4096] = 96MB)
    unsigned short* gmid  = kpt;                                      // A4 after kpT dead
    char* tail = w + 4 * SZ_ACT + (size_t)100663296;
    unsigned short* prjb = (unsigned short*)(tail);                   // 32768 B
    unsigned short* ctxb = (unsigned short*)(tail + 32768);           // 1572864 B
    float* ksum = (float*)(tail + 32768 + 1572864);                   // 49152 B
    float* kmax = (float*)(tail + 32768 + 1572864 + 49152);           // 4 B

    unsigned short* w1b = wow12 + 589824;
    unsigned short* w2b = wow12 + 2949120;
    unsigned short* wob = wow12;

    const float NORM = 0.35355339059327373f;  // 64^-0.25

    cvt_qkvp<<<1744, 256, 0, stream>>>(WQ, WK, WV, PRJ, wqkv, prjb, ksum, kmax);
    ln_kernel<true><<<16384, 256, 0, stream>>>(X, G1, Bn1, hbuf);
    // fused QKV: B = contiguous [2304][768] (wq|wk|wv); routes q->qn, k->kn, v->vT
    gemm_qkv<<<dim3(9, 64), 512, 0, stream>>>(hbuf, wqkv, BQ, BKb, BV, qn, kn, vtb, NORM);
    feat_kernel<1><<<dim3(64, 48), 256, 0, stream>>>(kn, prjb, nullptr, kmax, ksum);
    feat_kernel<2><<<dim3(64, 48), 256, 0, stream>>>(kn, prjb, kpt, kmax, ksum);  // A4: wqkv dead; ksum final
    ctx_gemm<<<dim3(16, 48), 256, 0, stream>>>(kpt, vtb, part);                    // A0: hbuf dead
    ctx_reduce<<<3072, 256, 0, stream>>>(part, ctxb);
    feat_attn<<<dim3(64, 48), 256, 0, stream>>>(qn, prjb, ctxb, ksum, attn);       // A3: vT dead; A4: kpT dead
    cvt_ow12<<<5184, 256, 0, stream>>>(WO, W1, W2, wow12);                         // A1: qn dead
    gemm_bt_256<1, true, false><<<dim3(3, 64), 512, 0, stream>>>(attn, wob, BO, X, x2, 768, 768, 1.0f);
    ln_kernel<false><<<16384, 256, 0, stream>>>(x2, G2, Bn2, hbuf);                // A0: part dead
    gemm_bt_256<2, false, false><<<dim3(12, 64), 512, 0, stream>>>(hbuf, w1b, Bf1, nullptr, gmid, 3072, 768, 1.0f);
    gemm_bt_256<1, false, true><<<dim3(3, 64), 512, 0, stream>>>(gmid, w2b, Bf2, x2, OUT, 768, 3072, 1.0f);
}